// Round 1
// baseline (17098.421 us; speedup 1.0000x reference)
//
#include <hip/hip_runtime.h>
#include <cstdint>

#define VOCAB 50257
#define VTOT  50321
#define TDEC  100
#define UNK   3
#define NBLK  256          // persistent decode blocks (1 per CU; all co-resident)
#define NTHR  512
#define VPB   198          // vocab rows per block (256*198 = 50688 >= 50321)

// ---------------- workspace layout (float offsets) ----------------
static const size_t OFF_EMB    = 0;        // [1024][128]
static const size_t OFF_WIHT_F = 131072;   // [128][640]
static const size_t OFF_WIHT_B = 212992;   // [128][640]
static const size_t OFF_WTE    = 294912;   // [320][320]
static const size_t OFF_XG     = 397312;   // [2][1024][640]
static const size_t OFF_ENCH   = 1708032;  // [1024][320]
static const size_t OFF_EPH    = 2035712;  // [1024][320]
static const size_t OFF_DECBUF = 2363392;  // [100][320]
static const size_t OFF_LOGITS = 2395392;  // 50688 (reused: attn-softmax partials)
static const size_t OFF_SCORES = 2446080;  // 1024  (reused: temporal values)
static const size_t OFF_GATES  = 2447104;  // 1280
static const size_t OFF_HPAR   = 2448384;  // [8][320]
static const size_t OFF_CPAR   = 2450944;  // [16][320]
static const size_t OFF_DCTX   = 2456064;  // 320
static const size_t OFF_H      = 2456384;  // 320 (unused now)
static const size_t OFF_H0     = 2456704;  // 320
static const size_t OFF_CA     = 2457024;  // 320 (unused now)
static const size_t OFF_CB     = 2457344;  // 320 (unused now)
static const size_t OFF_CUMA   = 2457664;  // 1024 (unused now)
static const size_t OFF_CUMB   = 2458688;  // 1024 (unused now)
static const size_t OFF_ATTN   = 2459712;  // 1024
static const size_t OFF_BM     = 2460736;  // 512 (use 256)
static const size_t OFF_BS     = 2461248;  // 512 (use 256)
static const size_t OFF_AVAL   = 2461760;  // 512 (use 256)
static const size_t OFF_AIDX   = 2462272;  // 512 (int, use 256)
static const size_t OFF_SCAL   = 2462784;  // reused: barrier state (2 ints)
static const size_t OFF_SKEY   = 2462848;  // 1024 (int)
static const size_t OFF_SPOS   = 2463872;  // 1024 (int)
static const size_t OFF_BSTART = 2464896;  // 513 (int; use 257)
static const size_t OFF_WBF16  = 2465792;  // bf16 out_proj, 50257*480 u32

static const size_t OFF_PMS  = OFF_LOGITS;   // [256][2] (m, sum-exp) attn partials
static const size_t OFF_TEMP = OFF_SCORES;   // [1024] temporal values
static const size_t OFF_BAR  = OFF_SCAL;     // int[2]: count, generation

__device__ __forceinline__ float sigmf(float x) { return 1.f / (1.f + expf(-x)); }

__device__ __forceinline__ float wsum64(float x) {
#pragma unroll
  for (int m = 1; m < 64; m <<= 1) x += __shfl_xor(x, m, 64);
  return x;
}

__device__ __forceinline__ unsigned short bf16r(float x) {
  uint32_t b = __float_as_uint(x);
  uint32_t r = (b + 0x7fffu + ((b >> 16) & 1u)) >> 16;
  return (unsigned short)r;
}

// device-wide barrier: sense via generation counter; agent-scope atomics;
// __threadfence() provides L2 writeback (release) / L2+L1 invalidate (acquire)
// which is required for cross-XCD visibility on gfx950.
__device__ __forceinline__ void gridbar(float* ws) {
  int* bar = (int*)(ws + OFF_BAR);
  __syncthreads();   // compiler emits waitcnt vmcnt(0) -> block's stores are in L2
  if (threadIdx.x == 0) {
    __threadfence(); // writeback L2 -> stores globally visible
    int g = __hip_atomic_load(&bar[1], __ATOMIC_RELAXED, __HIP_MEMORY_SCOPE_AGENT);
    int old = __hip_atomic_fetch_add(&bar[0], 1, __ATOMIC_ACQ_REL, __HIP_MEMORY_SCOPE_AGENT);
    if (old == NBLK - 1) {
      __hip_atomic_store(&bar[0], 0, __ATOMIC_RELAXED, __HIP_MEMORY_SCOPE_AGENT);
      __hip_atomic_store(&bar[1], g + 1, __ATOMIC_RELEASE, __HIP_MEMORY_SCOPE_AGENT);
    } else {
      while (__hip_atomic_load(&bar[1], __ATOMIC_RELAXED, __HIP_MEMORY_SCOPE_AGENT) == g)
        __builtin_amdgcn_s_sleep(2);
    }
    __threadfence(); // invalidate stale L1/L2 before reading others' data
  }
  __syncthreads();
}

// ---------------- P1: gather embeddings, transposes, state zero-init ----------------
__global__ __launch_bounds__(256) void k_setup(float* __restrict__ ws, const int* __restrict__ ids,
                                               const float* __restrict__ embt, const float* __restrict__ ewf,
                                               const float* __restrict__ ewb, const float* __restrict__ eap) {
  int idx = blockIdx.x * 256 + threadIdx.x;
  if (idx < 131072) {
    int tt = idx >> 7, e = idx & 127;
    int id = ids[tt]; if (id >= VOCAB) id = UNK;
    ws[OFF_EMB + idx] = embt[(size_t)id * 128 + e];
  } else if (idx < 212992) {
    int i = idx - 131072;
    int k = i / 640, g = i - (i / 640) * 640;
    ws[OFF_WIHT_F + i] = ewf[(size_t)g * 128 + k];
  } else if (idx < 294912) {
    int i = idx - 212992;
    int k = i / 640, g = i - (i / 640) * 640;
    ws[OFF_WIHT_B + i] = ewb[(size_t)g * 128 + k];
  } else if (idx < 397312) {
    int i = idx - 294912;
    int k = i / 320, j = i - (i / 320) * 320;
    ws[OFF_WTE + i] = eap[(size_t)j * 320 + k];
  }
}

// ---------------- P2: encoder x-part gates ----------------
__global__ __launch_bounds__(256) void k_xg(float* __restrict__ ws,
                                            const float* __restrict__ bif, const float* __restrict__ bhf,
                                            const float* __restrict__ bib, const float* __restrict__ bhb) {
  int idx = blockIdx.x * 256 + threadIdx.x;
  int d = idx / 655360;
  int r = idx - d * 655360;
  int tt = r / 640, g = r - (r / 640) * 640;
  const float* wT = ws + (d ? OFF_WIHT_B : OFF_WIHT_F);
  const float* er = ws + OFF_EMB + (size_t)(d ? (1023 - tt) : tt) * 128;
  float acc = d ? (bib[g] + bhb[g]) : (bif[g] + bhf[g]);
#pragma unroll 4
  for (int k = 0; k < 128; ++k) acc += er[k] * wT[(size_t)k * 640 + g];
  ws[OFF_XG + idx] = acc;
}

// ---------------- P3: out_proj = bf16(tanh(embedding @ vocab_proj)) ----------------
__global__ __launch_bounds__(256) void k_outproj(const float* __restrict__ embt, const float* __restrict__ vp,
                                                 float* __restrict__ ws) {
  __shared__ float As[64][128];
  __shared__ float Bs[128][64];
  const int tid = threadIdx.x;
  const int v0 = blockIdx.x * 64, n0 = blockIdx.y * 64;
  for (int c = 0; c < 32; ++c) {
    int idx = c * 256 + tid;
    int m = idx >> 7, k = idx & 127;
    int v = v0 + m;
    As[m][k] = (v < VOCAB) ? embt[(size_t)v * 128 + k] : 0.f;
    int k2 = idx >> 6, n = idx & 63;
    Bs[k2][n] = vp[(size_t)k2 * 960 + n0 + n];
  }
  __syncthreads();
  const int mi = tid >> 4, ni = tid & 15;
  float acc[4][4] = {};
  for (int k = 0; k < 128; ++k) {
    float a0 = As[mi * 4 + 0][k], a1 = As[mi * 4 + 1][k], a2 = As[mi * 4 + 2][k], a3 = As[mi * 4 + 3][k];
    float4 b = *(const float4*)&Bs[k][ni * 4];
    acc[0][0] += a0 * b.x; acc[0][1] += a0 * b.y; acc[0][2] += a0 * b.z; acc[0][3] += a0 * b.w;
    acc[1][0] += a1 * b.x; acc[1][1] += a1 * b.y; acc[1][2] += a1 * b.z; acc[1][3] += a1 * b.w;
    acc[2][0] += a2 * b.x; acc[2][1] += a2 * b.y; acc[2][2] += a2 * b.z; acc[2][3] += a2 * b.w;
    acc[3][0] += a3 * b.x; acc[3][1] += a3 * b.y; acc[3][2] += a3 * b.z; acc[3][3] += a3 * b.w;
  }
  unsigned short* W = (unsigned short*)(ws + OFF_WBF16);
#pragma unroll
  for (int i = 0; i < 4; ++i) {
    int v = v0 + mi * 4 + i;
    if (v < VOCAB) {
      ushort4 pk;
      pk.x = bf16r(tanhf(acc[i][0]));
      pk.y = bf16r(tanhf(acc[i][1]));
      pk.z = bf16r(tanhf(acc[i][2]));
      pk.w = bf16r(tanhf(acc[i][3]));
      *(ushort4*)&W[(size_t)v * 960 + n0 + ni * 4] = pk;
    }
  }
}

// ---------------- P4: sequential bi-LSTM encoder ----------------
__global__ __launch_bounds__(512) void k_encoder(float* __restrict__ ws, const float* __restrict__ whh_f,
                                                 const float* __restrict__ whh_b) {
  const int dir = blockIdx.x;
  const int tid = threadIdx.x;
  const float* whh = dir ? whh_b : whh_f;
  const float* xg = ws + OFF_XG + (size_t)dir * 655360;
  __shared__ float hbuf[160];
  __shared__ float part[4][640];
  const int q = tid & 127, kg = tid >> 7, ks = kg * 40;
  float w[5][40];
#pragma unroll
  for (int j = 0; j < 5; ++j)
#pragma unroll
    for (int i = 0; i < 40; ++i)
      w[j][i] = whh[(size_t)(5 * q + j) * 160 + ks + i];
  float cst = 0.f;
  if (tid < 160) hbuf[tid] = 0.f;
  __syncthreads();
  for (int t = 0; t < 1024; ++t) {
    float acc[5] = {0.f, 0.f, 0.f, 0.f, 0.f};
#pragma unroll
    for (int i4 = 0; i4 < 10; ++i4) {
      float4 h4 = *(const float4*)&hbuf[ks + i4 * 4];
#pragma unroll
      for (int j = 0; j < 5; ++j)
        acc[j] += w[j][i4 * 4 + 0] * h4.x + w[j][i4 * 4 + 1] * h4.y + w[j][i4 * 4 + 2] * h4.z + w[j][i4 * 4 + 3] * h4.w;
    }
#pragma unroll
    for (int j = 0; j < 5; ++j) part[kg][5 * q + j] = acc[j];
    __syncthreads();
    if (tid < 160) {
      float gi = xg[(size_t)t * 640 + tid];
      float gf = xg[(size_t)t * 640 + 160 + tid];
      float gg = xg[(size_t)t * 640 + 320 + tid];
      float go = xg[(size_t)t * 640 + 480 + tid];
#pragma unroll
      for (int k2 = 0; k2 < 4; ++k2) {
        gi += part[k2][tid]; gf += part[k2][160 + tid];
        gg += part[k2][320 + tid]; go += part[k2][480 + tid];
      }
      cst = sigmf(gf) * cst + sigmf(gi) * tanhf(gg);
      float hn = sigmf(go) * tanhf(cst);
      hbuf[tid] = hn;
      int trow = dir ? (1023 - t) : t;
      ws[OFF_ENCH + (size_t)trow * 320 + dir * 160 + tid] = hn;
    }
    __syncthreads();
  }
  if (tid < 160) ws[OFF_H0 + dir * 160 + tid] = hbuf[tid];
}

// ---------------- P5: enc_proj_h ----------------
__global__ __launch_bounds__(256) void k_encproj(float* __restrict__ ws) {
  int idx = blockIdx.x * 256 + threadIdx.x;
  int s = idx / 320, j = idx - (idx / 320) * 320;
  const float* er = ws + OFF_ENCH + (size_t)s * 320;
  const float* wt = ws + OFF_WTE;
  float acc = 0.f;
#pragma unroll 4
  for (int k = 0; k < 320; ++k) acc += er[k] * wt[(size_t)k * 320 + j];
  ws[OFF_EPH + idx] = acc;
}

// ---------------- P6: sort ids + slice table + barrier init ----------------
__global__ __launch_bounds__(512) void k_sort(float* __restrict__ ws, const int* __restrict__ ids) {
  __shared__ int sk[1024], sp[1024];
  const int tid = threadIdx.x;
  for (int j = tid; j < 1024; j += 512) { sk[j] = ids[j]; sp[j] = j; }
  __syncthreads();
  for (int k = 2; k <= 1024; k <<= 1)
    for (int j = k >> 1; j > 0; j >>= 1) {
      for (int i = tid; i < 1024; i += 512) {
        int ixj = i ^ j;
        if (ixj > i) {
          bool up = ((i & k) == 0);
          int a = sk[i], b2 = sk[ixj];
          if (up ? (a > b2) : (a < b2)) {
            sk[i] = b2; sk[ixj] = a;
            int pa = sp[i]; sp[i] = sp[ixj]; sp[ixj] = pa;
          }
        }
      }
      __syncthreads();
    }
  int* BST = (int*)(ws + OFF_BSTART);
  int* SK = (int*)(ws + OFF_SKEY);
  int* SP = (int*)(ws + OFF_SPOS);
  for (int j = tid; j < 1024; j += 512) {
    SK[j] = sk[j]; SP[j] = sp[j];
    int o1 = sk[j] / VPB;
    int o0 = (j == 0) ? -1 : (sk[j - 1] / VPB);
    for (int o = o0 + 1; o <= o1; ++o) BST[o] = j;
  }
  if (tid == 0) {
    int olast = sk[1023] / VPB;
    for (int o = olast + 1; o <= NBLK; ++o) BST[o] = 1024;
    int* bar = (int*)(ws + OFF_BAR);
    bar[0] = 0; bar[1] = 0;
  }
}

// ---------------- persistent decode: all 100 steps in one kernel ----------------
// 256 blocks x 512 threads (2048 waves = 1/4 device capacity -> all resident).
// Per step: A gates | B h,c,scores,hpar | C attn,enc_ctx,dec_ctx | D logits | E final
// separated by device-wide barriers. h,c,cum,concat,logits live in LDS.
__global__ __launch_bounds__(512) void k_decode(float* __restrict__ ws, float* __restrict__ out,
    const float* __restrict__ embt,
    const float* __restrict__ dwih, const float* __restrict__ dwhh,
    const float* __restrict__ dbih, const float* __restrict__ dbhh,
    const float* __restrict__ dap, const float* __restrict__ sw,
    const float* __restrict__ sb, const float* __restrict__ ob) {
  const int b = blockIdx.x, tid = threadIdx.x;
  const int l = tid & 63, w = tid >> 6;
  __shared__ float hL[320], cL[320];
  __shared__ __align__(16) float concatL[960];
  __shared__ float logitsL[VPB];
  __shared__ float tauL[4], cumL[4];
  __shared__ float redA[512], redB[512];
  __shared__ int   redI[512];
  __shared__ float attnL[64], dsL[128], daL[128], hpL[320];
  __shared__ float pcS;

  if (tid < 320) { hL[tid] = ws[OFF_H0 + tid]; cL[tid] = 0.f; }
  if (tid < 4) cumL[tid] = 0.f;
  __syncthreads();

  for (int t = 0; t < TDEC; ++t) {
    // ================= phase A: token argmax (replicated) + gate rows =================
    int token = 0;
    if (t > 0) {
      float av = -1e30f; int ai = 0;
      if (tid < 256) { av = ws[OFF_AVAL + tid]; ai = ((const int*)(ws + OFF_AIDX))[tid]; }
      redA[tid] = av; redI[tid] = ai;
      __syncthreads();
      for (int off = 256; off > 0; off >>= 1) {
        if (tid < off) {
          float v2 = redA[tid + off]; int i2 = redI[tid + off];
          if (v2 > redA[tid] || (v2 == redA[tid] && i2 < redI[tid])) { redA[tid] = v2; redI[tid] = i2; }
        }
        __syncthreads();
      }
      token = redI[0];
    }
    int tokm = (token >= VOCAB) ? UNK : token;
    if (w < 5) {  // rows 5b..5b+4 of the 1280 gates, one per warp
      const int r = 5 * b + w;
      float acc = dwih[(size_t)r * 128 + l] * embt[(size_t)tokm * 128 + l]
                + dwih[(size_t)r * 128 + 64 + l] * embt[(size_t)tokm * 128 + 64 + l];
#pragma unroll
      for (int c = 0; c < 5; ++c) acc += dwhh[(size_t)r * 320 + c * 64 + l] * hL[c * 64 + l];
      acc = wsum64(acc);
      if (l == 0) ws[OFF_GATES + r] = acc + dbih[r] + dbhh[r];
    }
    gridbar(ws);

    // ================= phase B: replicated h,c + score rows + hpar =================
    if (tid < 320) {
      float gi = ws[OFF_GATES + tid];
      float gf = ws[OFF_GATES + 320 + tid];
      float gg = ws[OFF_GATES + 640 + tid];
      float go = ws[OFF_GATES + 960 + tid];
      float c = sigmf(gf) * cL[tid] + sigmf(gi) * tanhf(gg);
      cL[tid] = c;
      float hn = sigmf(go) * tanhf(c);
      hL[tid] = hn;
      if (b == 17) ws[OFF_DECBUF + (size_t)t * 320 + tid] = hn;
    }
    __syncthreads();
    if (w < 4) {  // score rows 4b..4b+3, one per warp; temporal + cum local
      const int srow = 4 * b + w;
      const float* er = ws + OFF_EPH + (size_t)srow * 320;
      float acc = 0.f;
#pragma unroll
      for (int c = 0; c < 5; ++c) acc += er[c * 64 + l] * hL[c * 64 + l];
      acc = wsum64(acc);
      float tau = (t == 0) ? acc : expf(acc) / cumL[w];
      if (l == 0) {
        tauL[w] = tau;
        ws[OFF_TEMP + srow] = tau;
        cumL[w] += acc;
      }
    }
    if (b < 8 && tid < 320) {  // hpar partials (split over inner dim, 8 x 40)
      float acc = 0.f;
#pragma unroll 8
      for (int ii = 0; ii < 40; ++ii) {
        int i = b * 40 + ii;
        acc += hL[i] * dap[(size_t)i * 320 + tid];
      }
      ws[OFF_HPAR + b * 320 + tid] = acc;
    }
    __syncthreads();
    if (tid == 0) {  // per-block (max, sum-exp) softmax partial over 4 temporals
      float m4 = fmaxf(fmaxf(tauL[0], tauL[1]), fmaxf(tauL[2], tauL[3]));
      float s4 = expf(tauL[0] - m4) + expf(tauL[1] - m4) + expf(tauL[2] - m4) + expf(tauL[3] - m4);
      ws[OFF_PMS + 2 * b] = m4;
      ws[OFF_PMS + 2 * b + 1] = s4;
    }
    gridbar(ws);

    // ================= phase C: attn + enc_ctx partials (b<16) | dec attention (b==16) =================
    if (b < 16) {
      float m = -1e30f, s = 0.f;
      if (tid < 256) { m = ws[OFF_PMS + 2 * tid]; s = ws[OFF_PMS + 2 * tid + 1]; }
      redA[tid] = m; redB[tid] = s;
      __syncthreads();
      for (int off = 256; off > 0; off >>= 1) {
        if (tid < off) {
          float m1 = redA[tid], m2 = redA[tid + off];
          float mx = fmaxf(m1, m2);
          redB[tid] = redB[tid] * expf(m1 - mx) + redB[tid + off] * expf(m2 - mx);
          redA[tid] = mx;
        }
        __syncthreads();
      }
      const float M = redA[0], S = redB[0];
      __syncthreads();
      if (tid < 64) {
        float a = expf(ws[OFF_TEMP + 64 * b + tid] - M) / S;
        attnL[tid] = a;
        ws[OFF_ATTN + 64 * b + tid] = a;
      }
      __syncthreads();
      if (tid < 320) {
        float acc = 0.f;
        const float* eh = ws + OFF_ENCH + (size_t)(64 * b) * 320 + tid;
#pragma unroll 4
        for (int k2 = 0; k2 < 64; ++k2) acc += attnL[k2] * eh[(size_t)k2 * 320];
        ws[OFF_CPAR + b * 320 + tid] = acc;
      }
    } else if (b == 16) {
      if (tid < 320) {
        float a = 0.f;
#pragma unroll
        for (int q = 0; q < 8; ++q) a += ws[OFF_HPAR + q * 320 + tid];
        hpL[tid] = a;
      }
      __syncthreads();
      float hpv[5];
#pragma unroll
      for (int c = 0; c < 5; ++c) hpv[c] = hpL[c * 64 + l];
#pragma unroll
      for (int k2 = 0; k2 < 13; ++k2) {
        int tp = w + 8 * k2;
        if (tp < t) {
          float acc = 0.f;
#pragma unroll
          for (int c = 0; c < 5; ++c) acc += hpv[c] * ws[OFF_DECBUF + (size_t)tp * 320 + c * 64 + l];
          acc = wsum64(acc);
          if (l == 0) dsL[tp] = acc;
        }
      }
      __syncthreads();
      float dv = -1e30f;
      if (tid < 128) { dv = (tid < t) ? dsL[tid] : -1e30f; redA[tid] = dv; }
      __syncthreads();
      for (int off = 64; off > 0; off >>= 1) { if (tid < off) redA[tid] = fmaxf(redA[tid], redA[tid + off]); __syncthreads(); }
      float dmx = redA[0];
      __syncthreads();
      float de = (tid < 128) ? expf(dv - dmx) : 0.f;
      if (tid < 128) redA[tid] = de;
      __syncthreads();
      for (int off = 64; off > 0; off >>= 1) { if (tid < off) redA[tid] += redA[tid + off]; __syncthreads(); }
      float dS = redA[0];
      __syncthreads();
      if (tid < 128) daL[tid] = de / dS;
      __syncthreads();
      if (tid < 320) {
        float acc = 0.f;
        for (int tp = 0; tp < t; ++tp) acc += daL[tp] * ws[OFF_DECBUF + (size_t)tp * 320 + tid];
        ws[OFF_DCTX + tid] = (t == 0) ? 0.f : acc;
      }
    }
    gridbar(ws);

    // ================= phase D: concat + p_copy (replicated) + logits slice =================
    if (tid < 320) {
      float e = 0.f;
#pragma unroll
      for (int g2 = 0; g2 < 16; ++g2) e += ws[OFF_CPAR + g2 * 320 + tid];
      concatL[tid] = hL[tid];
      concatL[320 + tid] = e;
      concatL[640 + tid] = ws[OFF_DCTX + tid];
    }
    __syncthreads();
    if (w == 0) {
      float acc = 0.f;
#pragma unroll
      for (int c = 0; c < 15; ++c) acc += sw[c * 64 + l] * concatL[c * 64 + l];
      acc = wsum64(acc);
      if (l == 0) pcS = 1.f / (1.f + expf(-(acc + sb[0])));
    }
    {
      const unsigned* W = (const unsigned*)(ws + OFF_WBF16);
      const float2* cL2 = (const float2*)concatL;
      float cc0[7], cc1[7], ct0 = 0.f, ct1 = 0.f;
#pragma unroll
      for (int c = 0; c < 7; ++c) { float2 x = cL2[c * 64 + l]; cc0[c] = x.x; cc1[c] = x.y; }
      if (l < 32) { ct0 = concatL[896 + 2 * l]; ct1 = concatL[897 + 2 * l]; }
      const int vbase = b * VPB;
      const int r0 = w * 25, r1 = (w * 25 + 25 < VPB) ? (w * 25 + 25) : VPB;
      for (int r = r0; r < r1; r += 2) {
        int va = vbase + r, vb2 = va + 1;
        bool oka = (va < VOCAB);
        bool okb = (r + 1 < r1) && (vb2 < VOCAB);
        float acc0 = 0.f, acc1 = 0.f;
        const unsigned* rowa = W + (size_t)va * 480;
        const unsigned* rowb = W + (size_t)vb2 * 480;
        unsigned ua[7], ub[7], ta = 0, tb = 0;
        if (oka) {
#pragma unroll
          for (int c = 0; c < 7; ++c) ua[c] = rowa[c * 64 + l];
          if (l < 32) ta = rowa[448 + l];
        }
        if (okb) {
#pragma unroll
          for (int c = 0; c < 7; ++c) ub[c] = rowb[c * 64 + l];
          if (l < 32) tb = rowb[448 + l];
        }
        if (oka) {
#pragma unroll
          for (int c = 0; c < 7; ++c)
            acc0 += __uint_as_float(ua[c] << 16) * cc0[c] + __uint_as_float(ua[c] & 0xffff0000u) * cc1[c];
          if (l < 32) acc0 += __uint_as_float(ta << 16) * ct0 + __uint_as_float(ta & 0xffff0000u) * ct1;
        }
        if (okb) {
#pragma unroll
          for (int c = 0; c < 7; ++c)
            acc1 += __uint_as_float(ub[c] << 16) * cc0[c] + __uint_as_float(ub[c] & 0xffff0000u) * cc1[c];
          if (l < 32) acc1 += __uint_as_float(tb << 16) * ct0 + __uint_as_float(tb & 0xffff0000u) * ct1;
        }
        acc0 = wsum64(acc0);
        acc1 = wsum64(acc1);
        if (l == 0) {
          logitsL[r] = oka ? (acc0 + ob[va]) : -1e30f;
          if (r + 1 < r1) logitsL[r + 1] = okb ? (acc1 + ob[vb2]) : -1e30f;
        }
      }
    }
    __syncthreads();
    {
      float m = -1e30f, s = 0.f;
      if (tid < VPB) { float lv = logitsL[tid]; if (lv > -1e29f) { m = lv; s = 1.f; } }
      redA[tid] = m; redB[tid] = s;
      __syncthreads();
      for (int off = 256; off > 0; off >>= 1) {
        if (tid < off) {
          float m1 = redA[tid], m2 = redA[tid + off];
          float mx = fmaxf(m1, m2);
          redB[tid] = redB[tid] * expf(m1 - mx) + redB[tid + off] * expf(m2 - mx);
          redA[tid] = mx;
        }
        __syncthreads();
      }
      if (tid == 0) { ws[OFF_BM + b] = redA[0]; ws[OFF_BS + b] = redB[0]; }
    }
    gridbar(ws);

    // ================= phase E: global softmax combine + final + scatter + argmax =================
    {
      float m = -1e30f, s = 0.f;
      if (tid < 256) { m = ws[OFF_BM + tid]; s = ws[OFF_BS + tid]; }
      redA[tid] = m; redB[tid] = s;
      __syncthreads();
      for (int off = 256; off > 0; off >>= 1) {
        if (tid < off) {
          float m1 = redA[tid], m2 = redA[tid + off];
          float mx = fmaxf(m1, m2);
          redB[tid] = redB[tid] * expf(m1 - mx) + redB[tid + off] * expf(m2 - mx);
          redA[tid] = mx;
        }
        __syncthreads();
      }
      const float M = redA[0], Sg = redB[0];
      const float pc = pcS;
      const float scale = (1.f - pc) / Sg;
      __syncthreads();
      const int* BST = (const int*)(ws + OFF_BSTART);
      const int* SK = (const int*)(ws + OFF_SKEY);
      const int* SP = (const int*)(ws + OFF_SPOS);
      const int vbase = b * VPB;
      int v = vbase + tid;
      bool act = (tid < VPB) && (v < VTOT);
      float val = -1e30f;
      if (act) {
        val = (v < VOCAB) ? scale * expf(logitsL[tid] - M) : 0.f;
        int jb = BST[b], je = BST[b + 1];
        for (int j = jb; j < je; ++j)
          if (SK[j] == v) val += pc * ws[OFF_ATTN + SP[j]];
        out[(size_t)t * VTOT + v] = val;
      }
      redA[tid] = act ? val : -1e30f; redI[tid] = v;
      __syncthreads();
      for (int off = 256; off > 0; off >>= 1) {
        if (tid < off) {
          float v2 = redA[tid + off]; int i2 = redI[tid + off];
          if (v2 > redA[tid] || (v2 == redA[tid] && i2 < redI[tid])) { redA[tid] = v2; redI[tid] = i2; }
        }
        __syncthreads();
      }
      if (tid == 0) { ws[OFF_AVAL + b] = redA[0]; ((int*)(ws + OFF_AIDX))[b] = redI[0]; }
    }
    gridbar(ws);
  }
}

// ---------------- host ----------------
extern "C" void kernel_launch(void* const* d_in, const int* in_sizes, int n_in,
                              void* d_out, int out_size, void* d_ws, size_t ws_size,
                              hipStream_t stream) {
  const int*   ids  = (const int*)d_in[0];
  const float* embt = (const float*)d_in[1];
  const float* ewf  = (const float*)d_in[2];
  const float* ehf  = (const float*)d_in[3];
  const float* ebif = (const float*)d_in[4];
  const float* ebhf = (const float*)d_in[5];
  const float* ewb  = (const float*)d_in[6];
  const float* ehb  = (const float*)d_in[7];
  const float* ebib = (const float*)d_in[8];
  const float* ebhb = (const float*)d_in[9];
  const float* dwih = (const float*)d_in[10];
  const float* dwhh = (const float*)d_in[11];
  const float* dbih = (const float*)d_in[12];
  const float* dbhh = (const float*)d_in[13];
  const float* eap  = (const float*)d_in[14];
  const float* dap  = (const float*)d_in[15];
  const float* vp   = (const float*)d_in[16];
  const float* ob   = (const float*)d_in[17];
  const float* sw   = (const float*)d_in[18];
  const float* sb   = (const float*)d_in[19];
  float* out = (float*)d_out;
  float* ws  = (float*)d_ws;

  k_setup<<<1558, 256, 0, stream>>>(ws, ids, embt, ewf, ewb, eap);
  k_xg<<<5120, 256, 0, stream>>>(ws, ebif, ebhf, ebib, ebhb);
  k_outproj<<<dim3(786, 15), 256, 0, stream>>>(embt, vp, ws);
  k_encoder<<<2, 512, 0, stream>>>(ws, ehf, ehb);
  k_encproj<<<1280, 256, 0, stream>>>(ws);
  k_sort<<<1, 512, 0, stream>>>(ws, ids);
  k_decode<<<NBLK, NTHR, 0, stream>>>(ws, out, embt, dwih, dwhh, dbih, dbhh, dap, sw, sb, ob);
}

// Round 2
// 7076.078 us; speedup vs baseline: 2.4164x; 2.4164x over previous
//
#include <hip/hip_runtime.h>
#include <cstdint>

#define VOCAB 50257
#define VTOT  50321
#define TDEC  100
#define UNK   3
#define NBLK  256          // persistent decode blocks (1 per CU; all co-resident)
#define NTHR  512
#define VPB   198          // vocab rows per block (256*198 = 50688 >= 50321)

// ---------------- workspace layout (float offsets) ----------------
static const size_t OFF_EMB    = 0;        // [1024][128]
static const size_t OFF_WIHT_F = 131072;   // [128][640]
static const size_t OFF_WIHT_B = 212992;   // [128][640]
static const size_t OFF_WTE    = 294912;   // [320][320]
static const size_t OFF_XG     = 397312;   // [2][1024][640]
static const size_t OFF_ENCH   = 1708032;  // [1024][320]
static const size_t OFF_EPH    = 2035712;  // [1024][320]
static const size_t OFF_DECBUF = 2363392;  // [100][320] (private to block 16 during decode)
static const size_t OFF_LOGITS = 2395392;  // 50688 (reused: attn-softmax partials)
static const size_t OFF_SCORES = 2446080;  // 1024  (reused: temporal values)
static const size_t OFF_GATES  = 2447104;  // 1280
static const size_t OFF_HPAR   = 2448384;  // [8][320]
static const size_t OFF_CPAR   = 2450944;  // [16][320]
static const size_t OFF_DCTX   = 2456064;  // 320
static const size_t OFF_H      = 2456384;  // 320 (unused)
static const size_t OFF_H0     = 2456704;  // 320
static const size_t OFF_CA     = 2457024;  // 320 (unused)
static const size_t OFF_CB     = 2457344;  // 320 (unused)
static const size_t OFF_CUMA   = 2457664;  // 1024 (unused)
static const size_t OFF_CUMB   = 2458688;  // 1024 (unused)
static const size_t OFF_ATTN   = 2459712;  // 1024
static const size_t OFF_BM     = 2460736;  // 512 (use 256)
static const size_t OFF_BS     = 2461248;  // 512 (use 256)
static const size_t OFF_AVAL   = 2461760;  // 512 (use 256)
static const size_t OFF_AIDX   = 2462272;  // 512 (int, use 256)
static const size_t OFF_SCAL   = 2462784;  // reused: barrier state (64 ints)
static const size_t OFF_SKEY   = 2462848;  // 1024 (int)
static const size_t OFF_SPOS   = 2463872;  // 1024 (int)
static const size_t OFF_BSTART = 2464896;  // 513 (int; use 257)
static const size_t OFF_WBF16  = 2465792;  // bf16 out_proj, 50257*480 u32

static const size_t OFF_PMS  = OFF_LOGITS;   // [256][2] (m, sum-exp) attn partials
static const size_t OFF_TEMP = OFF_SCORES;   // [1024] temporal values
static const size_t OFF_BAR  = OFF_SCAL;     // int[64]: [0]=count, [32]=generation

__device__ __forceinline__ float sigmf(float x) { return 1.f / (1.f + expf(-x)); }

__device__ __forceinline__ float wsum64(float x) {
#pragma unroll
  for (int m = 1; m < 64; m <<= 1) x += __shfl_xor(x, m, 64);
  return x;
}

__device__ __forceinline__ unsigned short bf16r(float x) {
  uint32_t b = __float_as_uint(x);
  uint32_t r = (b + 0x7fffu + ((b >> 16) & 1u)) >> 16;
  return (unsigned short)r;
}

// coherent (fabric-point) accessors: compile to sc0/sc1 global ops, bypass L1/L2,
// per-word coherent across XCDs with NO cache flush/invalidate.
__device__ __forceinline__ float cload(const float* p) {
  return __hip_atomic_load((float*)p, __ATOMIC_RELAXED, __HIP_MEMORY_SCOPE_AGENT);
}
__device__ __forceinline__ void cstore(float* p, float v) {
  __hip_atomic_store(p, v, __ATOMIC_RELAXED, __HIP_MEMORY_SCOPE_AGENT);
}
__device__ __forceinline__ int cloadi(const int* p) {
  return __hip_atomic_load((int*)p, __ATOMIC_RELAXED, __HIP_MEMORY_SCOPE_AGENT);
}
__device__ __forceinline__ void cstorei(int* p, int v) {
  __hip_atomic_store(p, v, __ATOMIC_RELAXED, __HIP_MEMORY_SCOPE_AGENT);
}

// device-wide barrier with ZERO cache maintenance:
//  - all mutable cross-block data moves via cload/cstore (already coherent)
//  - s_waitcnt vmcnt(0) guarantees this block's coherent stores have reached
//    the coherent point before the arrival increment
//  - relaxed atomics on count/generation (separate cachelines)
__device__ __forceinline__ void gridbar(float* ws) {
  int* bar = (int*)(ws + OFF_BAR);
  __syncthreads();
  if (threadIdx.x == 0) {
    asm volatile("s_waitcnt vmcnt(0) lgkmcnt(0)" ::: "memory");
    int g = __hip_atomic_load(&bar[32], __ATOMIC_RELAXED, __HIP_MEMORY_SCOPE_AGENT);
    int old = __hip_atomic_fetch_add(&bar[0], 1, __ATOMIC_RELAXED, __HIP_MEMORY_SCOPE_AGENT);
    if (old == NBLK - 1) {
      __hip_atomic_store(&bar[0], 0, __ATOMIC_RELAXED, __HIP_MEMORY_SCOPE_AGENT);
      __hip_atomic_store(&bar[32], g + 1, __ATOMIC_RELAXED, __HIP_MEMORY_SCOPE_AGENT);
    } else {
      while (__hip_atomic_load(&bar[32], __ATOMIC_RELAXED, __HIP_MEMORY_SCOPE_AGENT) == g)
        __builtin_amdgcn_s_sleep(2);
    }
  }
  __syncthreads();
}

// ---------------- P1: gather embeddings, transposes ----------------
__global__ __launch_bounds__(256) void k_setup(float* __restrict__ ws, const int* __restrict__ ids,
                                               const float* __restrict__ embt, const float* __restrict__ ewf,
                                               const float* __restrict__ ewb, const float* __restrict__ eap) {
  int idx = blockIdx.x * 256 + threadIdx.x;
  if (idx < 131072) {
    int tt = idx >> 7, e = idx & 127;
    int id = ids[tt]; if (id >= VOCAB) id = UNK;
    ws[OFF_EMB + idx] = embt[(size_t)id * 128 + e];
  } else if (idx < 212992) {
    int i = idx - 131072;
    int k = i / 640, g = i - (i / 640) * 640;
    ws[OFF_WIHT_F + i] = ewf[(size_t)g * 128 + k];
  } else if (idx < 294912) {
    int i = idx - 212992;
    int k = i / 640, g = i - (i / 640) * 640;
    ws[OFF_WIHT_B + i] = ewb[(size_t)g * 128 + k];
  } else if (idx < 397312) {
    int i = idx - 294912;
    int k = i / 320, j = i - (i / 320) * 320;
    ws[OFF_WTE + i] = eap[(size_t)j * 320 + k];
  }
}

// ---------------- P2: encoder x-part gates ----------------
__global__ __launch_bounds__(256) void k_xg(float* __restrict__ ws,
                                            const float* __restrict__ bif, const float* __restrict__ bhf,
                                            const float* __restrict__ bib, const float* __restrict__ bhb) {
  int idx = blockIdx.x * 256 + threadIdx.x;
  int d = idx / 655360;
  int r = idx - d * 655360;
  int tt = r / 640, g = r - (r / 640) * 640;
  const float* wT = ws + (d ? OFF_WIHT_B : OFF_WIHT_F);
  const float* er = ws + OFF_EMB + (size_t)(d ? (1023 - tt) : tt) * 128;
  float acc = d ? (bib[g] + bhb[g]) : (bif[g] + bhf[g]);
#pragma unroll 4
  for (int k = 0; k < 128; ++k) acc += er[k] * wT[(size_t)k * 640 + g];
  ws[OFF_XG + idx] = acc;
}

// ---------------- P3: out_proj = bf16(tanh(embedding @ vocab_proj)) ----------------
__global__ __launch_bounds__(256) void k_outproj(const float* __restrict__ embt, const float* __restrict__ vp,
                                                 float* __restrict__ ws) {
  __shared__ float As[64][128];
  __shared__ float Bs[128][64];
  const int tid = threadIdx.x;
  const int v0 = blockIdx.x * 64, n0 = blockIdx.y * 64;
  for (int c = 0; c < 32; ++c) {
    int idx = c * 256 + tid;
    int m = idx >> 7, k = idx & 127;
    int v = v0 + m;
    As[m][k] = (v < VOCAB) ? embt[(size_t)v * 128 + k] : 0.f;
    int k2 = idx >> 6, n = idx & 63;
    Bs[k2][n] = vp[(size_t)k2 * 960 + n0 + n];
  }
  __syncthreads();
  const int mi = tid >> 4, ni = tid & 15;
  float acc[4][4] = {};
  for (int k = 0; k < 128; ++k) {
    float a0 = As[mi * 4 + 0][k], a1 = As[mi * 4 + 1][k], a2 = As[mi * 4 + 2][k], a3 = As[mi * 4 + 3][k];
    float4 b = *(const float4*)&Bs[k][ni * 4];
    acc[0][0] += a0 * b.x; acc[0][1] += a0 * b.y; acc[0][2] += a0 * b.z; acc[0][3] += a0 * b.w;
    acc[1][0] += a1 * b.x; acc[1][1] += a1 * b.y; acc[1][2] += a1 * b.z; acc[1][3] += a1 * b.w;
    acc[2][0] += a2 * b.x; acc[2][1] += a2 * b.y; acc[2][2] += a2 * b.z; acc[2][3] += a2 * b.w;
    acc[3][0] += a3 * b.x; acc[3][1] += a3 * b.y; acc[3][2] += a3 * b.z; acc[3][3] += a3 * b.w;
  }
  unsigned short* W = (unsigned short*)(ws + OFF_WBF16);
#pragma unroll
  for (int i = 0; i < 4; ++i) {
    int v = v0 + mi * 4 + i;
    if (v < VOCAB) {
      ushort4 pk;
      pk.x = bf16r(tanhf(acc[i][0]));
      pk.y = bf16r(tanhf(acc[i][1]));
      pk.z = bf16r(tanhf(acc[i][2]));
      pk.w = bf16r(tanhf(acc[i][3]));
      *(ushort4*)&W[(size_t)v * 960 + n0 + ni * 4] = pk;
    }
  }
}

// ---------------- P4: sequential bi-LSTM encoder ----------------
__global__ __launch_bounds__(512) void k_encoder(float* __restrict__ ws, const float* __restrict__ whh_f,
                                                 const float* __restrict__ whh_b) {
  const int dir = blockIdx.x;
  const int tid = threadIdx.x;
  const float* whh = dir ? whh_b : whh_f;
  const float* xg = ws + OFF_XG + (size_t)dir * 655360;
  __shared__ float hbuf[160];
  __shared__ float part[4][640];
  const int q = tid & 127, kg = tid >> 7, ks = kg * 40;
  float w[5][40];
#pragma unroll
  for (int j = 0; j < 5; ++j)
#pragma unroll
    for (int i = 0; i < 40; ++i)
      w[j][i] = whh[(size_t)(5 * q + j) * 160 + ks + i];
  float cst = 0.f;
  if (tid < 160) hbuf[tid] = 0.f;
  __syncthreads();
  for (int t = 0; t < 1024; ++t) {
    float acc[5] = {0.f, 0.f, 0.f, 0.f, 0.f};
#pragma unroll
    for (int i4 = 0; i4 < 10; ++i4) {
      float4 h4 = *(const float4*)&hbuf[ks + i4 * 4];
#pragma unroll
      for (int j = 0; j < 5; ++j)
        acc[j] += w[j][i4 * 4 + 0] * h4.x + w[j][i4 * 4 + 1] * h4.y + w[j][i4 * 4 + 2] * h4.z + w[j][i4 * 4 + 3] * h4.w;
    }
#pragma unroll
    for (int j = 0; j < 5; ++j) part[kg][5 * q + j] = acc[j];
    __syncthreads();
    if (tid < 160) {
      float gi = xg[(size_t)t * 640 + tid];
      float gf = xg[(size_t)t * 640 + 160 + tid];
      float gg = xg[(size_t)t * 640 + 320 + tid];
      float go = xg[(size_t)t * 640 + 480 + tid];
#pragma unroll
      for (int k2 = 0; k2 < 4; ++k2) {
        gi += part[k2][tid]; gf += part[k2][160 + tid];
        gg += part[k2][320 + tid]; go += part[k2][480 + tid];
      }
      cst = sigmf(gf) * cst + sigmf(gi) * tanhf(gg);
      float hn = sigmf(go) * tanhf(cst);
      hbuf[tid] = hn;
      int trow = dir ? (1023 - t) : t;
      ws[OFF_ENCH + (size_t)trow * 320 + dir * 160 + tid] = hn;
    }
    __syncthreads();
  }
  if (tid < 160) ws[OFF_H0 + dir * 160 + tid] = hbuf[tid];
}

// ---------------- P5: enc_proj_h ----------------
__global__ __launch_bounds__(256) void k_encproj(float* __restrict__ ws) {
  int idx = blockIdx.x * 256 + threadIdx.x;
  int s = idx / 320, j = idx - (idx / 320) * 320;
  const float* er = ws + OFF_ENCH + (size_t)s * 320;
  const float* wt = ws + OFF_WTE;
  float acc = 0.f;
#pragma unroll 4
  for (int k = 0; k < 320; ++k) acc += er[k] * wt[(size_t)k * 320 + j];
  ws[OFF_EPH + idx] = acc;
}

// ---------------- P6: sort ids + slice table + barrier init ----------------
__global__ __launch_bounds__(512) void k_sort(float* __restrict__ ws, const int* __restrict__ ids) {
  __shared__ int sk[1024], sp[1024];
  const int tid = threadIdx.x;
  for (int j = tid; j < 1024; j += 512) { sk[j] = ids[j]; sp[j] = j; }
  __syncthreads();
  for (int k = 2; k <= 1024; k <<= 1)
    for (int j = k >> 1; j > 0; j >>= 1) {
      for (int i = tid; i < 1024; i += 512) {
        int ixj = i ^ j;
        if (ixj > i) {
          bool up = ((i & k) == 0);
          int a = sk[i], b2 = sk[ixj];
          if (up ? (a > b2) : (a < b2)) {
            sk[i] = b2; sk[ixj] = a;
            int pa = sp[i]; sp[i] = sp[ixj]; sp[ixj] = pa;
          }
        }
      }
      __syncthreads();
    }
  int* BST = (int*)(ws + OFF_BSTART);
  int* SK = (int*)(ws + OFF_SKEY);
  int* SP = (int*)(ws + OFF_SPOS);
  for (int j = tid; j < 1024; j += 512) {
    SK[j] = sk[j]; SP[j] = sp[j];
    int o1 = sk[j] / VPB;
    int o0 = (j == 0) ? -1 : (sk[j - 1] / VPB);
    for (int o = o0 + 1; o <= o1; ++o) BST[o] = j;
  }
  if (tid == 0) {
    int olast = sk[1023] / VPB;
    for (int o = olast + 1; o <= NBLK; ++o) BST[o] = 1024;
    int* bar = (int*)(ws + OFF_BAR);
    bar[0] = 0; bar[32] = 0;
  }
}

// ---------------- persistent decode: all 100 steps in one kernel ----------------
// 256 blocks x 512 threads. Read-only data (W, EPH, ENCH, weights) uses plain
// cached loads and stays L2/L3-resident. Mutable cross-block data uses coherent
// cload/cstore. Barriers perform no cache maintenance.
__global__ __launch_bounds__(512) void k_decode(float* __restrict__ ws, float* __restrict__ out,
    const float* __restrict__ embt,
    const float* __restrict__ dwih, const float* __restrict__ dwhh,
    const float* __restrict__ dbih, const float* __restrict__ dbhh,
    const float* __restrict__ dap, const float* __restrict__ sw,
    const float* __restrict__ sb, const float* __restrict__ ob) {
  const int b = blockIdx.x, tid = threadIdx.x;
  const int l = tid & 63, w = tid >> 6;
  __shared__ float hL[320], cL[320];
  __shared__ __align__(16) float concatL[960];
  __shared__ float logitsL[VPB];
  __shared__ float tauL[4], cumL[4];
  __shared__ float redA[512], redB[512];
  __shared__ int   redI[512];
  __shared__ float attnL[64], dsL[128], daL[128], hpL[320];
  __shared__ float pcS;

  if (tid < 320) { hL[tid] = ws[OFF_H0 + tid]; cL[tid] = 0.f; }
  if (tid < 4) cumL[tid] = 0.f;
  __syncthreads();

  for (int t = 0; t < TDEC; ++t) {
    // ======= phase A: token argmax (replicated) + gate rows (5 per block) =======
    int token = 0;
    if (t > 0) {
      float av = -1e30f; int ai = 0;
      if (tid < 256) { av = cload(&ws[OFF_AVAL + tid]); ai = cloadi(((const int*)(ws + OFF_AIDX)) + tid); }
      redA[tid] = av; redI[tid] = ai;
      __syncthreads();
      for (int off = 256; off > 0; off >>= 1) {
        if (tid < off) {
          float v2 = redA[tid + off]; int i2 = redI[tid + off];
          if (v2 > redA[tid] || (v2 == redA[tid] && i2 < redI[tid])) { redA[tid] = v2; redI[tid] = i2; }
        }
        __syncthreads();
      }
      token = redI[0];
    }
    int tokm = (token >= VOCAB) ? UNK : token;
    if (w < 5) {  // rows 5b..5b+4 of the 1280 gates, one per warp
      const int r = 5 * b + w;
      float acc = dwih[(size_t)r * 128 + l] * embt[(size_t)tokm * 128 + l]
                + dwih[(size_t)r * 128 + 64 + l] * embt[(size_t)tokm * 128 + 64 + l];
#pragma unroll
      for (int c = 0; c < 5; ++c) acc += dwhh[(size_t)r * 320 + c * 64 + l] * hL[c * 64 + l];
      acc = wsum64(acc);
      if (l == 0) cstore(&ws[OFF_GATES + r], acc + dbih[r] + dbhh[r]);
    }
    gridbar(ws);

    // ======= phase B: replicated h,c + score rows + hpar partials =======
    if (tid < 320) {
      float gi = cload(&ws[OFF_GATES + tid]);
      float gf = cload(&ws[OFF_GATES + 320 + tid]);
      float gg = cload(&ws[OFF_GATES + 640 + tid]);
      float go = cload(&ws[OFF_GATES + 960 + tid]);
      float c = sigmf(gf) * cL[tid] + sigmf(gi) * tanhf(gg);
      cL[tid] = c;
      float hn = sigmf(go) * tanhf(c);
      hL[tid] = hn;
      if (b == 16) ws[OFF_DECBUF + (size_t)t * 320 + tid] = hn;  // private to block 16
    }
    __syncthreads();
    if (w < 4) {  // score rows 4b..4b+3, one per warp; temporal + cum block-local
      const int srow = 4 * b + w;
      const float* er = ws + OFF_EPH + (size_t)srow * 320;
      float acc = 0.f;
#pragma unroll
      for (int c = 0; c < 5; ++c) acc += er[c * 64 + l] * hL[c * 64 + l];
      acc = wsum64(acc);
      float tau = (t == 0) ? acc : expf(acc) / cumL[w];
      if (l == 0) {
        tauL[w] = tau;
        cstore(&ws[OFF_TEMP + srow], tau);
        cumL[w] += acc;
      }
    }
    if (b < 8 && tid < 320) {  // hpar partials (split over inner dim, 8 x 40)
      float acc = 0.f;
#pragma unroll 8
      for (int ii = 0; ii < 40; ++ii) {
        int i = b * 40 + ii;
        acc += hL[i] * dap[(size_t)i * 320 + tid];
      }
      cstore(&ws[OFF_HPAR + b * 320 + tid], acc);
    }
    __syncthreads();
    if (tid == 0) {  // per-block (max, sum-exp) softmax partial over 4 temporals
      float m4 = fmaxf(fmaxf(tauL[0], tauL[1]), fmaxf(tauL[2], tauL[3]));
      float s4 = expf(tauL[0] - m4) + expf(tauL[1] - m4) + expf(tauL[2] - m4) + expf(tauL[3] - m4);
      cstore(&ws[OFF_PMS + 2 * b], m4);
      cstore(&ws[OFF_PMS + 2 * b + 1], s4);
    }
    gridbar(ws);

    // ======= phase C: attn + enc_ctx partials (b<16) | dec attention (b==16) =======
    if (b < 16) {
      float m = -1e30f, s = 0.f;
      if (tid < 256) { m = cload(&ws[OFF_PMS + 2 * tid]); s = cload(&ws[OFF_PMS + 2 * tid + 1]); }
      redA[tid] = m; redB[tid] = s;
      __syncthreads();
      for (int off = 256; off > 0; off >>= 1) {
        if (tid < off) {
          float m1 = redA[tid], m2 = redA[tid + off];
          float mx = fmaxf(m1, m2);
          redB[tid] = redB[tid] * expf(m1 - mx) + redB[tid + off] * expf(m2 - mx);
          redA[tid] = mx;
        }
        __syncthreads();
      }
      const float M = redA[0], S = redB[0];
      __syncthreads();
      if (tid < 64) {
        float a = expf(cload(&ws[OFF_TEMP + 64 * b + tid]) - M) / S;
        attnL[tid] = a;
        cstore(&ws[OFF_ATTN + 64 * b + tid], a);
      }
      __syncthreads();
      if (tid < 320) {
        float acc = 0.f;
        const float* eh = ws + OFF_ENCH + (size_t)(64 * b) * 320 + tid;
#pragma unroll 4
        for (int k2 = 0; k2 < 64; ++k2) acc += attnL[k2] * eh[(size_t)k2 * 320];
        cstore(&ws[OFF_CPAR + b * 320 + tid], acc);
      }
    } else if (b == 16) {
      if (tid < 320) {
        float a = 0.f;
#pragma unroll
        for (int q = 0; q < 8; ++q) a += cload(&ws[OFF_HPAR + q * 320 + tid]);
        hpL[tid] = a;
      }
      __syncthreads();
      float hpv[5];
#pragma unroll
      for (int c = 0; c < 5; ++c) hpv[c] = hpL[c * 64 + l];
#pragma unroll
      for (int k2 = 0; k2 < 13; ++k2) {
        int tp = w + 8 * k2;
        if (tp < t) {
          float acc = 0.f;
#pragma unroll
          for (int c = 0; c < 5; ++c) acc += hpv[c] * ws[OFF_DECBUF + (size_t)tp * 320 + c * 64 + l];
          acc = wsum64(acc);
          if (l == 0) dsL[tp] = acc;
        }
      }
      __syncthreads();
      float dv = -1e30f;
      if (tid < 128) { dv = (tid < t) ? dsL[tid] : -1e30f; redA[tid] = dv; }
      __syncthreads();
      for (int off = 64; off > 0; off >>= 1) { if (tid < off) redA[tid] = fmaxf(redA[tid], redA[tid + off]); __syncthreads(); }
      float dmx = redA[0];
      __syncthreads();
      float de = (tid < 128) ? expf(dv - dmx) : 0.f;
      if (tid < 128) redA[tid] = de;
      __syncthreads();
      for (int off = 64; off > 0; off >>= 1) { if (tid < off) redA[tid] += redA[tid + off]; __syncthreads(); }
      float dS = redA[0];
      __syncthreads();
      if (tid < 128) daL[tid] = de / dS;
      __syncthreads();
      if (tid < 320) {
        float acc = 0.f;
        for (int tp = 0; tp < t; ++tp) acc += daL[tp] * ws[OFF_DECBUF + (size_t)tp * 320 + tid];
        cstore(&ws[OFF_DCTX + tid], (t == 0) ? 0.f : acc);
      }
    }
    gridbar(ws);

    // ======= phase D: concat + p_copy (replicated) + logits slice =======
    if (tid < 320) {
      float e = 0.f;
#pragma unroll
      for (int g2 = 0; g2 < 16; ++g2) e += cload(&ws[OFF_CPAR + g2 * 320 + tid]);
      concatL[tid] = hL[tid];
      concatL[320 + tid] = e;
      concatL[640 + tid] = cload(&ws[OFF_DCTX + tid]);
    }
    __syncthreads();
    if (w == 0) {
      float acc = 0.f;
#pragma unroll
      for (int c = 0; c < 15; ++c) acc += sw[c * 64 + l] * concatL[c * 64 + l];
      acc = wsum64(acc);
      if (l == 0) pcS = 1.f / (1.f + expf(-(acc + sb[0])));
    }
    {
      const unsigned* W = (const unsigned*)(ws + OFF_WBF16);
      const float2* cL2 = (const float2*)concatL;
      float cc0[7], cc1[7], ct0 = 0.f, ct1 = 0.f;
#pragma unroll
      for (int c = 0; c < 7; ++c) { float2 x = cL2[c * 64 + l]; cc0[c] = x.x; cc1[c] = x.y; }
      if (l < 32) { ct0 = concatL[896 + 2 * l]; ct1 = concatL[897 + 2 * l]; }
      const int vbase = b * VPB;
      const int r0 = w * 25, r1 = (w * 25 + 25 < VPB) ? (w * 25 + 25) : VPB;
      for (int r = r0; r < r1; r += 2) {
        int va = vbase + r, vb2 = va + 1;
        bool oka = (va < VOCAB);
        bool okb = (r + 1 < r1) && (vb2 < VOCAB);
        float acc0 = 0.f, acc1 = 0.f;
        const unsigned* rowa = W + (size_t)va * 480;
        const unsigned* rowb = W + (size_t)vb2 * 480;
        unsigned ua[7], ub[7], ta = 0, tb = 0;
        if (oka) {
#pragma unroll
          for (int c = 0; c < 7; ++c) ua[c] = rowa[c * 64 + l];
          if (l < 32) ta = rowa[448 + l];
        }
        if (okb) {
#pragma unroll
          for (int c = 0; c < 7; ++c) ub[c] = rowb[c * 64 + l];
          if (l < 32) tb = rowb[448 + l];
        }
        if (oka) {
#pragma unroll
          for (int c = 0; c < 7; ++c)
            acc0 += __uint_as_float(ua[c] << 16) * cc0[c] + __uint_as_float(ua[c] & 0xffff0000u) * cc1[c];
          if (l < 32) acc0 += __uint_as_float(ta << 16) * ct0 + __uint_as_float(ta & 0xffff0000u) * ct1;
        }
        if (okb) {
#pragma unroll
          for (int c = 0; c < 7; ++c)
            acc1 += __uint_as_float(ub[c] << 16) * cc0[c] + __uint_as_float(ub[c] & 0xffff0000u) * cc1[c];
          if (l < 32) acc1 += __uint_as_float(tb << 16) * ct0 + __uint_as_float(tb & 0xffff0000u) * ct1;
        }
        acc0 = wsum64(acc0);
        acc1 = wsum64(acc1);
        if (l == 0) {
          logitsL[r] = oka ? (acc0 + ob[va]) : -1e30f;
          if (r + 1 < r1) logitsL[r + 1] = okb ? (acc1 + ob[vb2]) : -1e30f;
        }
      }
    }
    __syncthreads();
    {
      float m = -1e30f, s = 0.f;
      if (tid < VPB) { float lv = logitsL[tid]; if (lv > -1e29f) { m = lv; s = 1.f; } }
      redA[tid] = m; redB[tid] = s;
      __syncthreads();
      for (int off = 256; off > 0; off >>= 1) {
        if (tid < off) {
          float m1 = redA[tid], m2 = redA[tid + off];
          float mx = fmaxf(m1, m2);
          redB[tid] = redB[tid] * expf(m1 - mx) + redB[tid + off] * expf(m2 - mx);
          redA[tid] = mx;
        }
        __syncthreads();
      }
      if (tid == 0) { cstore(&ws[OFF_BM + b], redA[0]); cstore(&ws[OFF_BS + b], redB[0]); }
    }
    gridbar(ws);

    // ======= phase E: global softmax combine + final + scatter + argmax =======
    {
      float m = -1e30f, s = 0.f;
      if (tid < 256) { m = cload(&ws[OFF_BM + tid]); s = cload(&ws[OFF_BS + tid]); }
      redA[tid] = m; redB[tid] = s;
      __syncthreads();
      for (int off = 256; off > 0; off >>= 1) {
        if (tid < off) {
          float m1 = redA[tid], m2 = redA[tid + off];
          float mx = fmaxf(m1, m2);
          redB[tid] = redB[tid] * expf(m1 - mx) + redB[tid + off] * expf(m2 - mx);
          redA[tid] = mx;
        }
        __syncthreads();
      }
      const float M = redA[0], Sg = redB[0];
      const float pc = pcS;
      const float scale = (1.f - pc) / Sg;
      __syncthreads();
      const int* BST = (const int*)(ws + OFF_BSTART);
      const int* SK = (const int*)(ws + OFF_SKEY);
      const int* SP = (const int*)(ws + OFF_SPOS);
      const int vbase = b * VPB;
      int v = vbase + tid;
      bool act = (tid < VPB) && (v < VTOT);
      float val = -1e30f;
      if (act) {
        val = (v < VOCAB) ? scale * expf(logitsL[tid] - M) : 0.f;
        int jb = BST[b], je = BST[b + 1];
        for (int j = jb; j < je; ++j)
          if (SK[j] == v) val += pc * cload(&ws[OFF_ATTN + SP[j]]);
        out[(size_t)t * VTOT + v] = val;
      }
      redA[tid] = act ? val : -1e30f; redI[tid] = v;
      __syncthreads();
      for (int off = 256; off > 0; off >>= 1) {
        if (tid < off) {
          float v2 = redA[tid + off]; int i2 = redI[tid + off];
          if (v2 > redA[tid] || (v2 == redA[tid] && i2 < redI[tid])) { redA[tid] = v2; redI[tid] = i2; }
        }
        __syncthreads();
      }
      if (tid == 0) { cstore(&ws[OFF_AVAL + b], redA[0]); cstorei(((int*)(ws + OFF_AIDX)) + b, redI[0]); }
    }
    gridbar(ws);
  }
}

// ---------------- host ----------------
extern "C" void kernel_launch(void* const* d_in, const int* in_sizes, int n_in,
                              void* d_out, int out_size, void* d_ws, size_t ws_size,
                              hipStream_t stream) {
  const int*   ids  = (const int*)d_in[0];
  const float* embt = (const float*)d_in[1];
  const float* ewf  = (const float*)d_in[2];
  const float* ehf  = (const float*)d_in[3];
  const float* ebif = (const float*)d_in[4];
  const float* ebhf = (const float*)d_in[5];
  const float* ewb  = (const float*)d_in[6];
  const float* ehb  = (const float*)d_in[7];
  const float* ebib = (const float*)d_in[8];
  const float* ebhb = (const float*)d_in[9];
  const float* dwih = (const float*)d_in[10];
  const float* dwhh = (const float*)d_in[11];
  const float* dbih = (const float*)d_in[12];
  const float* dbhh = (const float*)d_in[13];
  const float* eap  = (const float*)d_in[14];
  const float* dap  = (const float*)d_in[15];
  const float* vp   = (const float*)d_in[16];
  const float* ob   = (const float*)d_in[17];
  const float* sw   = (const float*)d_in[18];
  const float* sb   = (const float*)d_in[19];
  float* out = (float*)d_out;
  float* ws  = (float*)d_ws;

  k_setup<<<1558, 256, 0, stream>>>(ws, ids, embt, ewf, ewb, eap);
  k_xg<<<5120, 256, 0, stream>>>(ws, ebif, ebhf, ebib, ebhb);
  k_outproj<<<dim3(786, 15), 256, 0, stream>>>(embt, vp, ws);
  k_encoder<<<2, 512, 0, stream>>>(ws, ehf, ehb);
  k_encproj<<<1280, 256, 0, stream>>>(ws);
  k_sort<<<1, 512, 0, stream>>>(ws, ids);
  k_decode<<<NBLK, NTHR, 0, stream>>>(ws, out, embt, dwih, dwhh, dbih, dbhh, dap, sw, sb, ob);
}